// Round 10
// baseline (63.109 us; speedup 1.0000x reference)
//
#include <hip/hip_runtime.h>

#define B_  32
#define H_  512
#define W_  512
#define HW_ (H_ * W_)
#define NBLK_ 1024             // 1024 blocks * 4 waves = 4096 waves = 32 img * 128 row-quads
#define TPB_  256

typedef float f32x4 __attribute__((ext_vector_type(4)));

__device__ __forceinline__ float rcp_fast(float x) { return __builtin_amdgcn_rcpf(x); }

// WENO3, single fast-rcp form (validated rounds 1-9, absmax 0.0)
__device__ __forceinline__ float weno_minus(float vmm, float vm, float vp) {
    float d0 = vmm - vm, d1 = vm - vp;
    float t0 = 1e-6f + d0 * d0;
    float t1 = 1e-6f + d1 * d1;
    float s0 = t0 * t0, s1 = t1 * t1;
    float s0x2 = s0 + s0;
    float p0 = 1.5f * vm - 0.5f * vmm;
    float p1 = 0.5f * (vm + vp);
    return (s1 * p0 + s0x2 * p1) * rcp_fast(s1 + s0x2);
}

__device__ __forceinline__ float weno_plus(float vmm, float vm, float vp) {
    float d0 = vp - vm, d1 = vm - vmm;
    float t0 = 1e-6f + d0 * d0;
    float t1 = 1e-6f + d1 * d1;
    float s0 = t0 * t0, s1 = t1 * t1;
    float s0x2 = s0 + s0;
    float p0 = 1.5f * vm - 0.5f * vp;
    float p1 = 0.5f * (vm + vmm);
    return (s1 * p0 + s0x2 * p1) * rcp_fast(s1 + s0x2);
}

__device__ __forceinline__ void pixel_eval(
        float vxmm, float vxm, float vxc, float vxp,
        float vymm, float vym, float vyc, float vyp,
        float rh, float target, float lo, float hi,
        float& num, float& den) {
    float ux_minus = weno_minus(vxmm, vxm, vxc);
    float ux_plus  = weno_plus(vxm, vxc, vxp);
    float gx = fmaxf(fmaxf(ux_minus, -ux_plus), 0.0f);

    float uy_minus = weno_minus(vymm, vym, vyc);
    float uy_plus  = weno_plus(vym, vyc, vyp);
    float gy = fmaxf(fmaxf(uy_minus, -uy_plus), 0.0f);

    float gmag = __builtin_amdgcn_sqrtf(gx * gx + gy * gy + 1e-8f);

    float residual = gmag - target;
    float ar = fabsf(residual);
    float per_pixel = (ar < 0.01f) ? (50.0f * residual * residual)
                                   : (ar - 0.005f);

    bool m = (rh > 0.5f) && (gmag >= lo) && (gmag <= hi);
    // select (not multiply) so inf/NaN per_pixel at masked px can't poison num
    num += m ? per_pixel : 0.0f;
    den += m ? 1.0f : 0.0f;
}

// One full row (8 px/lane): c = center row, m2/m1/p1/p2 = y-neighbors, q = reach.
__device__ __forceinline__ void row_eval(
        f32x4 c0, f32x4 c1,
        f32x4 m2_0, f32x4 m2_1, f32x4 m1_0, f32x4 m1_1,
        f32x4 p1_0, f32x4 p1_1, f32x4 p2_0, f32x4 p2_1,
        f32x4 q0, f32x4 q1,
        int lane, float target, float lo, float hi,
        float& num, float& den) {
    float xm2 = __shfl_up(c1.z, 1);
    float xm1 = __shfl_up(c1.w, 1);
    float xp1 = __shfl_down(c0.x, 1);
    float xp2 = __shfl_down(c0.y, 1);
    if (lane == 0)  { xm2 = c0.x; xm1 = c0.x; }
    if (lane == 63) { xp1 = c1.w; xp2 = c1.w; }

    float D0  = xm1 - xm2;
    float D1  = c0.x - xm1;
    float D2  = c0.y - c0.x;
    float D3  = c0.z - c0.y;
    float D4  = c0.w - c0.z;
    float D5  = c1.x - c0.w;
    float D6  = c1.y - c1.x;
    float D7  = c1.z - c1.y;
    float D8  = c1.w - c1.z;
    float D9  = xp1 - c1.w;
    float D10 = xp2 - xp1;

    pixel_eval(D0, D1, D2, D3,
               m1_0.x - m2_0.x, c0.x - m1_0.x, p1_0.x - c0.x, p2_0.x - p1_0.x,
               q0.x, target, lo, hi, num, den);
    pixel_eval(D1, D2, D3, D4,
               m1_0.y - m2_0.y, c0.y - m1_0.y, p1_0.y - c0.y, p2_0.y - p1_0.y,
               q0.y, target, lo, hi, num, den);
    pixel_eval(D2, D3, D4, D5,
               m1_0.z - m2_0.z, c0.z - m1_0.z, p1_0.z - c0.z, p2_0.z - p1_0.z,
               q0.z, target, lo, hi, num, den);
    pixel_eval(D3, D4, D5, D6,
               m1_0.w - m2_0.w, c0.w - m1_0.w, p1_0.w - c0.w, p2_0.w - p1_0.w,
               q0.w, target, lo, hi, num, den);
    pixel_eval(D4, D5, D6, D7,
               m1_1.x - m2_1.x, c1.x - m1_1.x, p1_1.x - c1.x, p2_1.x - p1_1.x,
               q1.x, target, lo, hi, num, den);
    pixel_eval(D5, D6, D7, D8,
               m1_1.y - m2_1.y, c1.y - m1_1.y, p1_1.y - c1.y, p2_1.y - p1_1.y,
               q1.y, target, lo, hi, num, den);
    pixel_eval(D6, D7, D8, D9,
               m1_1.z - m2_1.z, c1.z - m1_1.z, p1_1.z - c1.z, p2_1.z - p1_1.z,
               q1.z, target, lo, hi, num, den);
    pixel_eval(D7, D8, D9, D10,
               m1_1.w - m2_1.w, c1.w - m1_1.w, p1_1.w - c1.w, p2_1.w - p1_1.w,
               q1.w, target, lo, hi, num, den);
}

__device__ __forceinline__ int clampy(int v) {
    return v < 0 ? 0 : (v > H_ - 1 ? H_ - 1 : v);
}

__global__ __launch_bounds__(TPB_, 4) void eikonal_main(
        const float* __restrict__ pred, const float* __restrict__ reach,
        double2* __restrict__ partials) {
    const float target = 1.0f / sqrtf((float)(511 * 511 + 511 * 511));
    const float lo = 0.3f * target;
    const float hi = 5.0f * target;

    int t = threadIdx.x;
    int lane = t & 63;

    // XCD-bijective swizzle (1024 % 8 == 0)
    int bswz = ((blockIdx.x & 7) << 7) + (blockIdx.x >> 3);
    // wave-uniform id -> all row addressing is SALU
    int wv = __builtin_amdgcn_readfirstlane((bswz << 2) + (t >> 6)); // 0..4095
    int b  = wv >> 7;            // image
    int y0 = (wv & 127) << 2;    // wave owns rows y0..y0+3

    const float* brow = pred + b * HW_;
    const float* rrow = reach + b * HW_;
    int x0 = lane << 3;          // 8 px per lane

    const float* rA = brow + (clampy(y0 - 2) << 9) + x0;
    const float* rB = brow + (clampy(y0 - 1) << 9) + x0;
    const float* rC = brow + ((y0    ) << 9) + x0;
    const float* rD = brow + ((y0 + 1) << 9) + x0;
    const float* rE = brow + ((y0 + 2) << 9) + x0;
    const float* rF = brow + ((y0 + 3) << 9) + x0;
    const float* rG = brow + (clampy(y0 + 4) << 9) + x0;
    const float* rH = brow + (clampy(y0 + 5) << 9) + x0;
    const float* qC = rrow + ((y0    ) << 9) + x0;
    const float* qD = rrow + ((y0 + 1) << 9) + x0;
    const float* qE = rrow + ((y0 + 2) << 9) + x0;
    const float* qF = rrow + ((y0 + 3) << 9) + x0;

    // ---- issue all 24 loads ----
    f32x4 pA0 = *(const f32x4*)(rA);  f32x4 pA1 = *(const f32x4*)(rA + 4);
    f32x4 pB0 = *(const f32x4*)(rB);  f32x4 pB1 = *(const f32x4*)(rB + 4);
    f32x4 pC0 = *(const f32x4*)(rC);  f32x4 pC1 = *(const f32x4*)(rC + 4);
    f32x4 pD0 = *(const f32x4*)(rD);  f32x4 pD1 = *(const f32x4*)(rD + 4);
    f32x4 pE0 = *(const f32x4*)(rE);  f32x4 pE1 = *(const f32x4*)(rE + 4);
    f32x4 pF0 = *(const f32x4*)(rF);  f32x4 pF1 = *(const f32x4*)(rF + 4);
    f32x4 pG0 = *(const f32x4*)(rG);  f32x4 pG1 = *(const f32x4*)(rG + 4);
    f32x4 pH0 = *(const f32x4*)(rH);  f32x4 pH1 = *(const f32x4*)(rH + 4);
    f32x4 qC0 = *(const f32x4*)(qC);  f32x4 qC1 = *(const f32x4*)(qC + 4);
    f32x4 qD0 = *(const f32x4*)(qD);  f32x4 qD1 = *(const f32x4*)(qD + 4);
    f32x4 qE0 = *(const f32x4*)(qE);  f32x4 qE1 = *(const f32x4*)(qE + 4);
    f32x4 qF0 = *(const f32x4*)(qF);  f32x4 qF1 = *(const f32x4*)(qF + 4);

    // Pin all loads live here: the allocator cannot sink loads to uses, so all
    // 24 are issued before one wait point (r9-validated idiom, -13%).
    asm volatile("" ::
        "v"(pA0), "v"(pA1), "v"(pB0), "v"(pB1),
        "v"(pC0), "v"(pC1), "v"(pD0), "v"(pD1),
        "v"(pE0), "v"(pE1), "v"(pF0), "v"(pF1),
        "v"(pG0), "v"(pG1), "v"(pH0), "v"(pH1),
        "v"(qC0), "v"(qC1), "v"(qD0), "v"(qD1),
        "v"(qE0), "v"(qE1), "v"(qF0), "v"(qF1));
    __builtin_amdgcn_sched_barrier(0);

    float num = 0.0f, den = 0.0f;

    row_eval(pC0, pC1, pA0, pA1, pB0, pB1, pD0, pD1, pE0, pE1,
             qC0, qC1, lane, target, lo, hi, num, den);
    row_eval(pD0, pD1, pB0, pB1, pC0, pC1, pE0, pE1, pF0, pF1,
             qD0, qD1, lane, target, lo, hi, num, den);
    row_eval(pE0, pE1, pC0, pC1, pD0, pD1, pF0, pF1, pG0, pG1,
             qE0, qE1, lane, target, lo, hi, num, den);
    row_eval(pF0, pF1, pD0, pD1, pE0, pE1, pG0, pG1, pH0, pH1,
             qF0, qF1, lane, target, lo, hi, num, den);

    // ---- block reduction (4 waves) ----
    double dn = (double)num;
    double dd = (double)den;
    #pragma unroll
    for (int off = 32; off > 0; off >>= 1) {
        dn += __shfl_down(dn, off);
        dd += __shfl_down(dd, off);
    }
    __shared__ double sn[4], sd[4];
    int wid = t >> 6;
    if (lane == 0) { sn[wid] = dn; sd[wid] = dd; }
    __syncthreads();
    if (t == 0) {
        double2 p;
        p.x = sn[0] + sn[1] + sn[2] + sn[3];
        p.y = sd[0] + sd[1] + sd[2] + sd[3];
        partials[blockIdx.x] = p;
    }
}

__global__ __launch_bounds__(256) void eikonal_finalize(
        const double2* __restrict__ partials, float* __restrict__ out) {
    int t = threadIdx.x;
    double n = 0.0, d = 0.0;
    #pragma unroll
    for (int k = 0; k < NBLK_ / 256; ++k) {
        double2 p = partials[t + (k << 8)];
        n += p.x;
        d += p.y;
    }
    #pragma unroll
    for (int off = 32; off > 0; off >>= 1) {
        n += __shfl_down(n, off);
        d += __shfl_down(d, off);
    }
    __shared__ double sn[4], sd[4];
    int wid = t >> 6;
    int lane = t & 63;
    if (lane == 0) { sn[wid] = n; sd[wid] = d; }
    __syncthreads();
    if (t == 0) {
        double num = sn[0] + sn[1] + sn[2] + sn[3];
        double den = sd[0] + sd[1] + sd[2] + sd[3];
        if (den < 1e-8) den = 1e-8;
        out[0] = (float)(num / den);
    }
}

extern "C" void kernel_launch(void* const* d_in, const int* in_sizes, int n_in,
                              void* d_out, int out_size, void* d_ws, size_t ws_size,
                              hipStream_t stream) {
    const float* pred  = (const float*)d_in[0];
    const float* reach = (const float*)d_in[1];
    float* out = (float*)d_out;
    double2* partials = (double2*)d_ws;   // 1024 * 16B = 16 KB, fully rewritten each call

    eikonal_main<<<NBLK_, TPB_, 0, stream>>>(pred, reach, partials);
    eikonal_finalize<<<1, 256, 0, stream>>>(partials, out);
}